// Round 14
// baseline (299.546 us; speedup 1.0000x reference)
//
#include <hip/hip_runtime.h>
#include <hip/hip_bf16.h>
#include <stdint.h>

// EvolvedLoopLinear: out[b,j] = sum_i x[b,i]*W[j,i] + b[j]
// M=8192, N=4096, K=4096. fp32 in/out, bf16 MFMA compute.
// Round 14: window-decoupled pipeline. BK=32 => tile == window:
//   [12 ds_reads of tile T+1's fragments | 4 gld_lds stage tile T+3 |
//    32 MFMA on tile T's fragments (ZERO same-window waits) |
//    vmcnt(4) | barrier]
// MFMA operands were read one barrier earlier -> no exposed DS latency
// (the r5-r13 plateau cause). Pipeline liveness = 2 fragment sets
// (96 VGPR) + acc(128 AGPR) = r13's proven no-spill budget (unlike r7's
// full-double which spilled). 4 LDS buffers (128 KiB), stage distance 3,
// counted vmcnt(4)/tile (ledger: steady 8 outstanding, retires T+2;
// prologue stages t0-t2, vmcnt(4) -> t0,t1 resident). LDS layout =
// r11's paired-row [128][64] + XOR swizzle (HW-measured 0 conflicts at
// BK=32). One barrier per tile. T1 XCD swizzle, T5 setprio, r4 fences.

typedef __bf16 bf16_t;
typedef __bf16 bf16x8 __attribute__((ext_vector_type(8)));
typedef float  f32x4  __attribute__((ext_vector_type(4)));

#define M_DIM 8192
#define N_DIM 4096
#define K_DIM 4096
#define NT    (K_DIM / 32)   // 128 K-tiles of BK=32
#define NITER (NT / 4)       // 32 iterations, 4 tiles each (static buf idx)
#define BUFE  16384          // elements per buffer (32 KB): A 8192 | B 8192

#define GLD16(gp, lp) __builtin_amdgcn_global_load_lds(                    \
    (const __attribute__((address_space(1))) void*)(gp),                   \
    (__attribute__((address_space(3))) void*)(lp), 16, 0, 0)

#define MFMA(a, b, c) __builtin_amdgcn_mfma_f32_16x16x32_bf16((a), (b), (c), 0, 0, 0)

#define FENCE() asm volatile("" ::: "memory")

// ---------------- fp32 -> bf16 convert (vectorized, grid-stride) -----------
__global__ void __launch_bounds__(256) cvt_f32_bf16(
    const float* __restrict__ in, bf16_t* __restrict__ out, long n8)
{
    long i0 = (long)blockIdx.x * blockDim.x + threadIdx.x;
    long stride = (long)gridDim.x * blockDim.x;
    for (long i = i0; i < n8; i += stride) {
        const float4* p = (const float4*)(in + i * 8);
        float4 a = p[0];
        float4 b = p[1];
        bf16x8 o;
        o[0] = (bf16_t)a.x; o[1] = (bf16_t)a.y; o[2] = (bf16_t)a.z; o[3] = (bf16_t)a.w;
        o[4] = (bf16_t)b.x; o[5] = (bf16_t)b.y; o[6] = (bf16_t)b.z; o[7] = (bf16_t)b.w;
        *(bf16x8*)(out + i * 8) = o;
    }
}

// ---------------- 256x256 bf16 GEMM, window-decoupled, 4-buffer BK=32 ------
// Buffer q (16384 el): A @q*BUFE as paired-row [128][64] (256 M-rows),
// B @+8192 as paired-row [128][64] (256 N-rows). Element (r,k) of a tile:
// ldsrow = r>>1, within-row = (r&1)*32 + k; stored 16B-chunk slot =
// chunk ^ (ldsrow & 7)  [r11 layout, HW-verified 0 conflicts].
__global__ void __launch_bounds__(512, 1) gemm_256_wd(
    const bf16_t* __restrict__ A, const bf16_t* __restrict__ B,
    const float* __restrict__ bias, float* __restrict__ C)
{
    __shared__ bf16_t sm[4 * BUFE];   // 128 KiB

    // XCD-aware bijective swizzle (gridDim = 512, divisible by 8)
    const int nwg = gridDim.x;
    const int bid = blockIdx.x;
    const int cpx = nwg >> 3;
    const int swz = (bid & 7) * cpx + (bid >> 3);
    const int NBN = N_DIM / 256;                       // 16
    const long blockM = (long)(swz / NBN) * 256;
    const long blockN = (long)(swz % NBN) * 256;

    const int t    = threadIdx.x;
    const int lane = t & 63;
    const int wid  = t >> 6;        // 8 waves: 2 (M) x 4 (N)
    const int wr   = wid >> 2;      // 0..1 -> 128 rows each
    const int wc   = wid & 3;       // 0..3 -> 64 cols each
    const int l15  = lane & 15;
    const int lk   = lane >> 4;     // 0..3

    // ---- staging (r11 formulas, refcheck-passed): thread t -> ldsrow
    // sr=t>>3, slot s=t&7, global chunk c = s^(sr&7), global row =
    // 2*sr + (c>>2), k-chunk = (c&3)*8. Line 1 of each region: +128 rows.
    const int sr = t >> 3;
    const int c  = (t & 7) ^ (sr & 7);
    const int grow = 2 * sr + (c >> 2);
    const int kc8  = (c & 3) * 8;
    const bf16_t* gA = A + (blockM + grow) * (long)K_DIM + kc8;
    const bf16_t* gB = B + (blockN + grow) * (long)K_DIM + kc8;
    const int dstT = t * 8;         // 16 B per thread, linear within line

    // ---- fragment reads (r11 formulas): frag f row = base + f*16 + l15,
    // k = lk*8. ldsrow = base/2 + f*8 + (l15>>1); slot =
    // ((l15&1)*4 + lk) ^ (l15>>1).
    const int slotA = ((((l15 & 1) << 2) + lk) ^ (l15 >> 1)) << 3;
    const int aBase = (wr * 64 + (l15 >> 1)) * 64 + slotA;          // +f*512
    const int bBase = 8192 + (wc * 32 + (l15 >> 1)) * 64 + slotA;   // +f*512

    f32x4 acc[8][4] = {};

#define STAGE(q, tk) do {                                                  \
    bf16_t* _l = (bf16_t*)sm + (q) * BUFE + dstT;                          \
    GLD16(gA + (long)(tk) * 32,                _l);                        \
    GLD16(gA + (long)(tk) * 32 + 128L * K_DIM, _l + 4096);                 \
    GLD16(gB + (long)(tk) * 32,                _l + 8192);                 \
    GLD16(gB + (long)(tk) * 32 + 128L * K_DIM, _l + 12288); } while (0)

    bf16x8 aE[8], bE[4], aO[8], bO[4];

#define READ_SET(Q, AV, BV) do {                                           \
    const bf16_t* _s = (const bf16_t*)sm + (Q) * BUFE;                     \
    _Pragma("unroll") for (int f = 0; f < 4; ++f)                          \
        BV[f] = *(const bf16x8*)(_s + bBase + f * 512);                    \
    _Pragma("unroll") for (int f = 0; f < 8; ++f)                          \
        AV[f] = *(const bf16x8*)(_s + aBase + f * 512); } while (0)

    // 32 MFMA, all-distinct accumulators (no intra-cluster deps);
    // operands were read in the PREVIOUS window -> zero waits.
#define MFMA_SET(AV, BV) do {                                              \
    __builtin_amdgcn_s_setprio(1);                                         \
    _Pragma("unroll") for (int m = 0; m < 8; ++m)                          \
    _Pragma("unroll") for (int n = 0; n < 4; ++n)                          \
        acc[m][n] = MFMA(AV[m], BV[n], acc[m][n]);                         \
    __builtin_amdgcn_s_setprio(0); } while (0)

#define VM4() asm volatile("s_waitcnt vmcnt(4)" ::: "memory")
#define VM0() asm volatile("s_waitcnt vmcnt(0)" ::: "memory")
#define TILE_END()                                                         \
    __builtin_amdgcn_sched_barrier(0);                                     \
    __builtin_amdgcn_s_barrier();                                          \
    FENCE()

    // prologue: stage t0,t1,t2 (12 loads, fence-pinned groups);
    // vmcnt(4) -> t0,t1 resident; read tile0 fragments into E set.
    STAGE(0, 0); FENCE();
    STAGE(1, 1); FENCE();
    STAGE(2, 2); FENCE();
    VM4();
    TILE_END();
    READ_SET(0, aE, bE);

    for (int i = 0; i < NITER; ++i) {
        const int tkb = 4 * i;
        const bool last = (i == NITER - 1);

        // ---- tile tkb+0 (buf0, set E): read t+1 -> O; stage t+3 -> buf3
        READ_SET(1, aO, bO);
        STAGE(3, tkb + 3);
        FENCE();
        MFMA_SET(aE, bE);
        VM4();
        TILE_END();

        // ---- tile tkb+1 (buf1, set O): read t+1 -> E; stage t+4 -> buf0
        READ_SET(2, aE, bE);
        if (!last) STAGE(0, tkb + 4);
        FENCE();
        MFMA_SET(aO, bO);
        if (!last) VM4(); else VM0();
        TILE_END();

        // ---- tile tkb+2 (buf2, set E): read t+1 -> O; stage t+5 -> buf1
        READ_SET(3, aO, bO);
        if (!last) STAGE(1, tkb + 5);
        FENCE();
        MFMA_SET(aE, bE);
        if (!last) VM4(); else VM0();
        TILE_END();

        // ---- tile tkb+3 (buf3, set O): read t+1 -> E; stage t+6 -> buf2
        if (!last) {
            READ_SET(0, aE, bE);
            STAGE(2, tkb + 6);
        }
        FENCE();
        MFMA_SET(aO, bO);
        if (!last) VM4(); else VM0();
        TILE_END();
    }

#undef STAGE

    // epilogue: C/D layout col = lane&15, row = (lane>>4)*4 + j
    const long cb = blockN + wc * 64;
    float bv[4];
    long  cn[4];
#pragma unroll
    for (int n = 0; n < 4; ++n) {
        cn[n] = cb + n * 16 + l15;
        bv[n] = bias[cn[n]];
    }
#pragma unroll
    for (int m = 0; m < 8; ++m) {
        const long r0 = blockM + wr * 128 + m * 16 + lk * 4;
#pragma unroll
        for (int n = 0; n < 4; ++n)
#pragma unroll
            for (int j = 0; j < 4; ++j)
                C[(r0 + j) * (long)N_DIM + cn[n]] = acc[m][n][j] + bv[n];
    }
}

// ---------------- fp32 fallback (only if ws too small) ---------------------
__global__ void __launch_bounds__(256) gemm_f32_fallback(
    const float* __restrict__ A, const float* __restrict__ W,
    const float* __restrict__ bias, float* __restrict__ C)
{
    __shared__ float sA[64][17];
    __shared__ float sB[64][17];
    const int bm = blockIdx.y, bn = blockIdx.x;
    const int t = threadIdx.x;
    const int tx = t & 15, ty = t >> 4;
    const long row0 = (long)bm * 64, col0 = (long)bn * 64;
    float acc[4][4] = {};
    for (int kt = 0; kt < K_DIM; kt += 16) {
        const int r = t >> 2, c = (t & 3) * 4;
        float4 a4 = *(const float4*)&A[(row0 + r) * K_DIM + kt + c];
        float4 b4 = *(const float4*)&W[(col0 + r) * K_DIM + kt + c];
        sA[r][c] = a4.x; sA[r][c + 1] = a4.y; sA[r][c + 2] = a4.z; sA[r][c + 3] = a4.w;
        sB[r][c] = b4.x; sB[r][c + 1] = b4.y; sB[r][c + 2] = b4.z; sB[r][c + 3] = b4.w;
        __syncthreads();
#pragma unroll
        for (int kk = 0; kk < 16; ++kk) {
            float av[4], bv[4];
#pragma unroll
            for (int i = 0; i < 4; ++i) av[i] = sA[ty * 4 + i][kk];
#pragma unroll
            for (int j = 0; j < 4; ++j) bv[j] = sB[tx * 4 + j][kk];
#pragma unroll
            for (int i = 0; i < 4; ++i)
#pragma unroll
                for (int j = 0; j < 4; ++j) acc[i][j] += av[i] * bv[j];
        }
        __syncthreads();
    }
#pragma unroll
    for (int i = 0; i < 4; ++i)
#pragma unroll
        for (int j = 0; j < 4; ++j)
            C[(row0 + ty * 4 + i) * N_DIM + col0 + tx * 4 + j] =
                acc[i][j] + bias[col0 + tx * 4 + j];
}

extern "C" void kernel_launch(void* const* d_in, const int* in_sizes, int n_in,
                              void* d_out, int out_size, void* d_ws, size_t ws_size,
                              hipStream_t stream)
{
    const float* x = (const float*)d_in[0];   // [8192, 4096]
    const float* W = (const float*)d_in[1];   // [4096, 4096]
    const float* b = (const float*)d_in[2];   // [4096]
    float* out = (float*)d_out;               // [8192, 4096] fp32

    const long xe = (long)M_DIM * K_DIM;
    const long we = (long)N_DIM * K_DIM;
    const size_t need = (size_t)(xe + we) * sizeof(bf16_t);  // ~96 MiB

    if (ws_size >= need) {
        bf16_t* xb = (bf16_t*)d_ws;
        bf16_t* wb = xb + xe;
        cvt_f32_bf16<<<2048, 256, 0, stream>>>(x, xb, xe / 8);
        cvt_f32_bf16<<<1024, 256, 0, stream>>>(W, wb, we / 8);
        gemm_256_wd<<<(M_DIM / 256) * (N_DIM / 256), 512, 0, stream>>>(xb, wb, b, out);
    } else {
        dim3 grid(N_DIM / 64, M_DIM / 64);
        gemm_f32_fallback<<<grid, 256, 0, stream>>>(x, W, b, out);
    }
}

// Round 15
// 268.808 us; speedup vs baseline: 1.1144x; 1.1144x over previous
//
#include <hip/hip_runtime.h>
#include <hip/hip_bf16.h>
#include <stdint.h>

// EvolvedLoopLinear: out[b,j] = sum_i x[b,i]*W[j,i] + b[j]
// M=8192, N=4096, K=4096. fp32 in/out, bf16 MFMA compute.
// Round 15: r9 (champion) with the read->MFMA FENCE removed. Each phase:
//   STAGE (gld_lds) -> FENCE (pins vmcnt ledger order only) ->
//   ds_reads + MFMA cluster freely interleaved by the compiler
//   (register deps + counted lgkmcnt waits) -> FENCE -> barrier -> FENCE.
// Every read's consumer is in-phase, so reads retire before the barrier
// (WAR publication identical to r9); gld_lds<->vmcnt order unchanged
// (RAW ledger identical). The only change is scheduling freedom: the
// 12-read issue burst folds into the 16-MFMA cluster instead of
// serializing ahead of it (the measured ~1830 cyc/tile overhead).

typedef __bf16 bf16_t;
typedef __bf16 bf16x8 __attribute__((ext_vector_type(8)));
typedef float  f32x4  __attribute__((ext_vector_type(4)));

#define M_DIM 8192
#define N_DIM 4096
#define K_DIM 4096
#define NT    (K_DIM / 64)    // 64 K-tiles of BK=64
#define NITER (NT / 2)        // 32 iterations, 2 K-tiles each

#define GLD16(gp, lp) __builtin_amdgcn_global_load_lds(                    \
    (const __attribute__((address_space(1))) void*)(gp),                   \
    (__attribute__((address_space(3))) void*)(lp), 16, 0, 0)

#define MFMA(a, b, c) __builtin_amdgcn_mfma_f32_16x16x32_bf16((a), (b), (c), 0, 0, 0)

#define FENCE() asm volatile("" ::: "memory")

// ---------------- fp32 -> bf16 convert (vectorized, grid-stride) -----------
__global__ void __launch_bounds__(256) cvt_f32_bf16(
    const float* __restrict__ in, bf16_t* __restrict__ out, long n8)
{
    long i0 = (long)blockIdx.x * blockDim.x + threadIdx.x;
    long stride = (long)gridDim.x * blockDim.x;
    for (long i = i0; i < n8; i += stride) {
        const float4* p = (const float4*)(in + i * 8);
        float4 a = p[0];
        float4 b = p[1];
        bf16x8 o;
        o[0] = (bf16_t)a.x; o[1] = (bf16_t)a.y; o[2] = (bf16_t)a.z; o[3] = (bf16_t)a.w;
        o[4] = (bf16_t)b.x; o[5] = (bf16_t)b.y; o[6] = (bf16_t)b.z; o[7] = (bf16_t)b.w;
        *(bf16x8*)(out + i * 8) = o;
    }
}

// ---------------- 256x256 8-phase bf16 GEMM (A,B row-major [*,K]) ----------
// LDS per parity buffer q (32768 el): Am0 @0, Am1 @8192, Bn0 @16384,
// Bn1 @24576. Chunk swizzle within each region: slot = chunk ^ (rho&7).
__global__ void __launch_bounds__(512, 1) gemm_256_8ph(
    const bf16_t* __restrict__ A, const bf16_t* __restrict__ B,
    const float* __restrict__ bias, float* __restrict__ C)
{
    __shared__ bf16_t sm[2 * 32768];   // 128 KiB

    // XCD-aware bijective swizzle (gridDim = 512, divisible by 8)
    const int nwg = gridDim.x;
    const int bid = blockIdx.x;
    const int cpx = nwg >> 3;
    const int swz = (bid & 7) * cpx + (bid >> 3);
    const int NBN = N_DIM / 256;                       // 16
    const long blockM = (long)(swz / NBN) * 256;
    const long blockN = (long)(swz % NBN) * 256;

    const int t    = threadIdx.x;
    const int lane = t & 63;
    const int wid  = t >> 6;        // 8 waves: 2 (M) x 4 (N)
    const int wr   = wid >> 2;      // 0..1 -> 128 rows each
    const int wc   = wid & 3;       // 0..3 -> 64 cols each
    const int l15  = lane & 15;
    const int lk   = lane >> 4;     // 0..3

    // staging: LDS dest linear (t*16B within region line); global src row
    // per region mapping, chunk carries inverse swizzle. (r9 verbatim)
    const int cg  = (t & 7) ^ ((t >> 3) & 7);
    const int rA0 = (t >> 3);                                  // A line-0 row
    const int rB0 = ((t >> 3) & 31) | (((t >> 3) & 32) << 1);  // B line-0 row
    const bf16_t* gA = A + (blockM + rA0) * (long)K_DIM + cg * 8;
    const bf16_t* gB = B + (blockN + rB0) * (long)K_DIM + cg * 8;
    const int dstT = t * 8;         // 16 B per thread, linear within line

    // read side (r9 verbatim): fragment rho&7 == l15&7 for all fragments
    const int swzr = l15 & 7;
    const int cOff0 = ((0 * 4 + lk) ^ swzr) << 3;
    const int cOff1 = ((1 * 4 + lk) ^ swzr) << 3;
    const int aBase = wr * 4096 + l15 * 64;            // within Am region
    const int bBase = 16384 + wc * 2048 + l15 * 64;    // within buffer (Bn0)

    f32x4 acc[8][4] = {};

#define STAGE_A(q, tk, h) do {                                             \
    const bf16_t* _g = gA + (long)(tk) * 64 + (long)(h) * 64 * K_DIM;      \
    bf16_t* _l = (bf16_t*)sm + (q) * 32768 + (h) * 8192 + dstT;            \
    GLD16(_g,                _l);                                          \
    GLD16(_g + 128L * K_DIM, _l + 4096); } while (0)

#define STAGE_B(q, tk, h) do {                                             \
    const bf16_t* _g = gB + (long)(tk) * 64 + (long)(h) * 32 * K_DIM;      \
    bf16_t* _l = (bf16_t*)sm + (q) * 32768 + 16384 + (h) * 8192 + dstT;    \
    GLD16(_g,                _l);                                          \
    GLD16(_g + 128L * K_DIM, _l + 4096); } while (0)

    bf16x8 a0[4][2], a1[4][2], b0[2][2], b1[2][2];

#define READ_A0B0(s) do {                                                  \
    _Pragma("unroll") for (int n = 0; n < 2; ++n) {                        \
        b0[n][0] = *(const bf16x8*)((s) + bBase + n * 1024 + cOff0);       \
        b0[n][1] = *(const bf16x8*)((s) + bBase + n * 1024 + cOff1);       \
    }                                                                      \
    _Pragma("unroll") for (int m = 0; m < 4; ++m) {                        \
        a0[m][0] = *(const bf16x8*)((s) + aBase + m * 1024 + cOff0);       \
        a0[m][1] = *(const bf16x8*)((s) + aBase + m * 1024 + cOff1);       \
    } } while (0)

#define READ_B1(s) do {                                                    \
    _Pragma("unroll") for (int n = 0; n < 2; ++n) {                        \
        b1[n][0] = *(const bf16x8*)((s) + bBase + 8192 + n * 1024 + cOff0);\
        b1[n][1] = *(const bf16x8*)((s) + bBase + 8192 + n * 1024 + cOff1);\
    } } while (0)

#define READ_A1(s) do {                                                    \
    _Pragma("unroll") for (int m = 0; m < 4; ++m) {                        \
        a1[m][0] = *(const bf16x8*)((s) + 8192 + aBase + m * 1024 + cOff0);\
        a1[m][1] = *(const bf16x8*)((s) + 8192 + aBase + m * 1024 + cOff1);\
    } } while (0)

    // MFMA clusters (m-outer: group m needs only b(4 reads) + a[m](2))
#define MFMA_Q0() do { _Pragma("unroll") for (int m = 0; m < 4; ++m)       \
    _Pragma("unroll") for (int kk = 0; kk < 2; ++kk)                       \
    _Pragma("unroll") for (int n = 0; n < 2; ++n)                          \
        acc[m][n] = MFMA(a0[m][kk], b0[n][kk], acc[m][n]); } while (0)
#define MFMA_Q1() do { _Pragma("unroll") for (int m = 0; m < 4; ++m)       \
    _Pragma("unroll") for (int kk = 0; kk < 2; ++kk)                       \
    _Pragma("unroll") for (int n = 0; n < 2; ++n)                          \
        acc[m][2 + n] = MFMA(a0[m][kk], b1[n][kk], acc[m][2 + n]); } while (0)
#define MFMA_Q2() do { _Pragma("unroll") for (int m = 0; m < 4; ++m)       \
    _Pragma("unroll") for (int kk = 0; kk < 2; ++kk)                       \
    _Pragma("unroll") for (int n = 0; n < 2; ++n)                          \
        acc[4 + m][n] = MFMA(a1[m][kk], b0[n][kk], acc[4 + m][n]); } while (0)
#define MFMA_Q3() do { _Pragma("unroll") for (int m = 0; m < 4; ++m)       \
    _Pragma("unroll") for (int kk = 0; kk < 2; ++kk)                       \
    _Pragma("unroll") for (int n = 0; n < 2; ++n)                          \
        acc[4 + m][2 + n] = MFMA(a1[m][kk], b1[n][kk], acc[4 + m][2 + n]); } while (0)

    // phase close-out: fence (reads can't sink below), barrier, fence.
#define END_BARRIER()                                                      \
    FENCE();                                                               \
    __builtin_amdgcn_s_barrier();                                          \
    FENCE()

    // prologue: tile0 all 4 regions (8 loads) | tile1 minus Am1 (6 loads).
    STAGE_A(0, 0, 0); STAGE_A(0, 0, 1); STAGE_B(0, 0, 0); STAGE_B(0, 0, 1);
    FENCE();
    STAGE_A(1, 1, 0); STAGE_B(1, 1, 0); STAGE_B(1, 1, 1);
    FENCE();
    asm volatile("s_waitcnt vmcnt(6)" ::: "memory");   // tile0 landed
    __builtin_amdgcn_sched_barrier(0);
    __builtin_amdgcn_s_barrier();
    FENCE();

    const bf16_t* s0 = (const bf16_t*)sm;           // buf0 (even tiles)
    const bf16_t* s1 = (const bf16_t*)sm + 32768;   // buf1 (odd tiles)

    for (int i = 0; i < NITER; ++i) {
        const int tk0 = 2 * i;
        const int tk1 = 2 * i + 1;
        const bool full = (i < NITER - 1);

        // ===== P1: stage Am1(b1,tk1) | reads b0,a0(s0) ∥ MFMA q0 =====
        STAGE_A(1, tk1, 1);
        FENCE();
        READ_A0B0(s0);
        __builtin_amdgcn_s_setprio(1);
        MFMA_Q0();
        __builtin_amdgcn_s_setprio(0);
        END_BARRIER();

        // ===== P2: stage Am0(b0,tk0+2) | reads b1(s0) ∥ MFMA q1 =====
        if (full) STAGE_A(0, tk0 + 2, 0);
        FENCE();
        READ_B1(s0);
        __builtin_amdgcn_s_setprio(1);
        MFMA_Q1();
        __builtin_amdgcn_s_setprio(0);
        END_BARRIER();

        // ===== P3: stage Bn0(b0,tk0+2) | reads a1(s0) ∥ MFMA q2 =====
        if (full) STAGE_B(0, tk0 + 2, 0);
        FENCE();
        READ_A1(s0);
        __builtin_amdgcn_s_setprio(1);
        MFMA_Q2();
        __builtin_amdgcn_s_setprio(0);
        END_BARRIER();

        // ===== P4: stage Bn1(b0,tk0+2) | MFMA q3; vmcnt(6) =====
        if (full) STAGE_B(0, tk0 + 2, 1);
        FENCE();
        __builtin_amdgcn_s_setprio(1);
        MFMA_Q3();
        __builtin_amdgcn_s_setprio(0);
        if (full) asm volatile("s_waitcnt vmcnt(6)" ::: "memory");
        else      asm volatile("s_waitcnt vmcnt(0)" ::: "memory");
        __builtin_amdgcn_sched_barrier(0);
        END_BARRIER();

        // ===== P5: stage Am1(b0,tk0+2) | reads b0,a0(s1) ∥ MFMA q0 =====
        if (full) STAGE_A(0, tk0 + 2, 1);
        FENCE();
        READ_A0B0(s1);
        __builtin_amdgcn_s_setprio(1);
        MFMA_Q0();
        __builtin_amdgcn_s_setprio(0);
        END_BARRIER();

        // ===== P6: stage Am0(b1,tk1+2) | reads b1(s1) ∥ MFMA q1 =====
        if (full) STAGE_A(1, tk1 + 2, 0);
        FENCE();
        READ_B1(s1);
        __builtin_amdgcn_s_setprio(1);
        MFMA_Q1();
        __builtin_amdgcn_s_setprio(0);
        END_BARRIER();

        // ===== P7: stage Bn0(b1,tk1+2) | reads a1(s1) ∥ MFMA q2 =====
        if (full) STAGE_B(1, tk1 + 2, 0);
        FENCE();
        READ_A1(s1);
        __builtin_amdgcn_s_setprio(1);
        MFMA_Q2();
        __builtin_amdgcn_s_setprio(0);
        END_BARRIER();

        // ===== P8: stage Bn1(b1,tk1+2) | MFMA q3; vmcnt(6) =====
        if (full) STAGE_B(1, tk1 + 2, 1);
        FENCE();
        __builtin_amdgcn_s_setprio(1);
        MFMA_Q3();
        __builtin_amdgcn_s_setprio(0);
        if (full) asm volatile("s_waitcnt vmcnt(6)" ::: "memory");
        else      asm volatile("s_waitcnt vmcnt(0)" ::: "memory");
        __builtin_amdgcn_sched_barrier(0);
        END_BARRIER();
    }

#undef STAGE_A
#undef STAGE_B

    // epilogue: C/D layout col = lane&15, row = (lane>>4)*4 + j
    const long cb = blockN + wc * 64;
    float bv[4];
    long  cn[4];
#pragma unroll
    for (int n = 0; n < 4; ++n) {
        cn[n] = cb + n * 16 + l15;
        bv[n] = bias[cn[n]];
    }
#pragma unroll
    for (int m = 0; m < 8; ++m) {
        const long r0 = blockM + wr * 128 + m * 16 + lk * 4;
#pragma unroll
        for (int n = 0; n < 4; ++n)
#pragma unroll
            for (int j = 0; j < 4; ++j)
                C[(r0 + j) * (long)N_DIM + cn[n]] = acc[m][n][j] + bv[n];
    }
}

// ---------------- fp32 fallback (only if ws too small) ---------------------
__global__ void __launch_bounds__(256) gemm_f32_fallback(
    const float* __restrict__ A, const float* __restrict__ W,
    const float* __restrict__ bias, float* __restrict__ C)
{
    __shared__ float sA[64][17];
    __shared__ float sB[64][17];
    const int bm = blockIdx.y, bn = blockIdx.x;
    const int t = threadIdx.x;
    const int tx = t & 15, ty = t >> 4;
    const long row0 = (long)bm * 64, col0 = (long)bn * 64;
    float acc[4][4] = {};
    for (int kt = 0; kt < K_DIM; kt += 16) {
        const int r = t >> 2, c = (t & 3) * 4;
        float4 a4 = *(const float4*)&A[(row0 + r) * K_DIM + kt + c];
        float4 b4 = *(const float4*)&W[(col0 + r) * K_DIM + kt + c];
        sA[r][c] = a4.x; sA[r][c + 1] = a4.y; sA[r][c + 2] = a4.z; sA[r][c + 3] = a4.w;
        sB[r][c] = b4.x; sB[r][c + 1] = b4.y; sB[r][c + 2] = b4.z; sB[r][c + 3] = b4.w;
        __syncthreads();
#pragma unroll
        for (int kk = 0; kk < 16; ++kk) {
            float av[4], bv[4];
#pragma unroll
            for (int i = 0; i < 4; ++i) av[i] = sA[ty * 4 + i][kk];
#pragma unroll
            for (int j = 0; j < 4; ++j) bv[j] = sB[tx * 4 + j][kk];
#pragma unroll
            for (int i = 0; i < 4; ++i)
#pragma unroll
                for (int j = 0; j < 4; ++j) acc[i][j] += av[i] * bv[j];
        }
        __syncthreads();
    }
#pragma unroll
    for (int i = 0; i < 4; ++i)
#pragma unroll
        for (int j = 0; j < 4; ++j)
            C[(row0 + ty * 4 + i) * N_DIM + col0 + tx * 4 + j] =
                acc[i][j] + bias[col0 + tx * 4 + j];
}

extern "C" void kernel_launch(void* const* d_in, const int* in_sizes, int n_in,
                              void* d_out, int out_size, void* d_ws, size_t ws_size,
                              hipStream_t stream)
{
    const float* x = (const float*)d_in[0];   // [8192, 4096]
    const float* W = (const float*)d_in[1];   // [4096, 4096]
    const float* b = (const float*)d_in[2];   // [4096]
    float* out = (float*)d_out;               // [8192, 4096] fp32

    const long xe = (long)M_DIM * K_DIM;
    const long we = (long)N_DIM * K_DIM;
    const size_t need = (size_t)(xe + we) * sizeof(bf16_t);  // ~96 MiB

    if (ws_size >= need) {
        bf16_t* xb = (bf16_t*)d_ws;
        bf16_t* wb = xb + xe;
        cvt_f32_bf16<<<2048, 256, 0, stream>>>(x, xb, xe / 8);
        cvt_f32_bf16<<<1024, 256, 0, stream>>>(W, wb, we / 8);
        gemm_256_8ph<<<(M_DIM / 256) * (N_DIM / 256), 512, 0, stream>>>(xb, wb, b, out);
    } else {
        dim3 grid(N_DIM / 64, M_DIM / 64);
        gemm_f32_fallback<<<grid, 256, 0, stream>>>(x, W, b, out);
    }
}